// Round 22
// baseline (57.512 us; speedup 1.0000x reference)
//
#include <hip/hip_runtime.h>
#include <hip/hip_bf16.h>

using f32x4    = __attribute__((ext_vector_type(4))) float;
using f32x16   = __attribute__((ext_vector_type(16))) float;
using bf16x8   = __attribute__((ext_vector_type(8))) __bf16;
using ushort8  = __attribute__((ext_vector_type(8))) unsigned short;
using ushort4v = __attribute__((ext_vector_type(4))) unsigned short;
using uint4v   = __attribute__((ext_vector_type(4))) unsigned int;
using float4v  = __attribute__((ext_vector_type(4))) float;

#define LOG2E 1.44269504088896340736f
#define SHIFT_L2 5.77078016355585f   // 4 * log2(e): p = exp(s_true - 4)

static __device__ __forceinline__ unsigned short f2bf(float f) {
  union { __hip_bfloat16 h; unsigned short u; } cv;
  cv.h = __float2bfloat16(f);
  return cv.u;
}
static __device__ __forceinline__ bf16x8 ld_bf8_g(const void* p) {
  ushort8 u = *(const ushort8*)p;
  return __builtin_bit_cast(bf16x8, u);
}
static __device__ __forceinline__ float fast_exp2(float x) {
#if __has_builtin(__builtin_amdgcn_exp2f)
  return __builtin_amdgcn_exp2f(x);
#else
  return exp2f(x);
#endif
}
static __device__ __forceinline__ unsigned int pk2(float a, float b) {
  return (unsigned int)f2bf(a) | ((unsigned int)f2bf(b) << 16);
}

// ---- W prep: Wfrag in MFMA B-fragment order (validated layout) ------------
__global__ __launch_bounds__(256) void wprep_kernel(
    const float* __restrict__ wq, const float* __restrict__ wk,
    const float* __restrict__ wv, unsigned short* __restrict__ Wfrag) {
  int idx = blockIdx.x * 256 + threadIdx.x;   // 0 .. 196607
  int col = idx >> 10;                        // 0..191
  int k   = idx & 1023;
  const float* w = (col < 64) ? wq : (col < 128) ? wk : wv;
  int c = col & 63;
  int n = col >> 4, l15 = col & 15;
  int kk = k >> 5, lh = (k >> 3) & 3, e = k & 7;
  size_t elem = ((size_t)(n * 32 + kk) * 64 + lh * 16 + l15) * 8 + e;
  Wfrag[elem] = f2bf(w[k * 64 + c]);
}

// ---- QKV projection v5: BK=128 (8 steps, half the barriers) ---------------
// B direct-from-L2 (Wfrag) ping-pong over 32-k chunk-pairs (R19 cadence);
// A async reg->LDS dbuf (16 fp32/thread/step, depth-2 step ring). One raw
// s_barrier + lgkmcnt(0) per 128-k step. BM=32, BN=192.
__global__ __launch_bounds__(256, 2) void proj_kernel(
    const float* __restrict__ x, const unsigned short* __restrict__ Wfrag,
    const float* __restrict__ bq, const float* __restrict__ bk,
    const float* __restrict__ bv,
    unsigned short* __restrict__ qb, unsigned short* __restrict__ kreg,
    unsigned short* __restrict__ vreg) {
  __shared__ __align__(16) char As[2][32 * 256];   // dbuf [32 rows][128 k] bf16
  int tid = threadIdx.x, wave = tid >> 6, lane = tid & 63;
  int rowBase = blockIdx.x * 32;
  int rhalf = (wave & 1) * 16;
  int nbase = (wave >> 1) * 6;          // 6 n-tiles of 16 cols per wave-pair
  int l15 = lane & 15, lh = lane >> 4;

  int arow = tid >> 3, ac8 = (tid & 7); // A-stage: 16 fp32 per thread
  const float* xp = x + (size_t)(rowBase + arow) * 1024 + ac8 * 16;
  int abyte = (arow * 256 + ac8 * 32) ^ ((arow & 7) << 4);
  const char* wfb = (const char*)Wfrag + (size_t)lane * 16;

  f32x4 acc[6];
#pragma unroll
  for (int i = 0; i < 6; ++i) acc[i] = (f32x4){0.f, 0.f, 0.f, 0.f};

  float4v aR[2][4];          // A step-ring: slot s holds A(step) step%2==s
  bf16x8 B[2][12];           // B ping-pong over chunk-pairs kkp (0..15)

  // ---- prologue: A(0)->buf0 via temps; A(1),A(2) in flight; B(kkp=0) ----
  {
    float4v t0 = *(const float4v*)(xp);
    float4v t1 = *(const float4v*)(xp + 4);
    float4v t2 = *(const float4v*)(xp + 8);
    float4v t3 = *(const float4v*)(xp + 12);
#pragma unroll
    for (int j = 0; j < 6; ++j) {
      B[0][j * 2]     = ld_bf8_g(wfb + (((size_t)(nbase + j) * 32 + 0) << 10));
      B[0][j * 2 + 1] = ld_bf8_g(wfb + (((size_t)(nbase + j) * 32 + 1) << 10));
    }
    ushort8 u0, u1;
#pragma unroll
    for (int e = 0; e < 4; ++e) {
      u0[e] = f2bf(t0[e]); u0[4 + e] = f2bf(t1[e]);
      u1[e] = f2bf(t2[e]); u1[4 + e] = f2bf(t3[e]);
    }
    *(ushort8*)(As[0] + abyte) = u0;
    *(ushort8*)(As[0] + (abyte ^ 16)) = u1;
  }
#pragma unroll
  for (int d = 1; d <= 2; ++d)
#pragma unroll
    for (int q4 = 0; q4 < 4; ++q4)
      aR[d & 1][q4] = *(const float4v*)(xp + d * 128 + q4 * 4);
  asm volatile("s_waitcnt lgkmcnt(0)" ::: "memory");
  __builtin_amdgcn_s_barrier();
  __builtin_amdgcn_sched_barrier(0);

#pragma unroll
  for (int kt2 = 0; kt2 < 8; ++kt2) {
    const int cur = kt2 & 1, nxt = cur ^ 1;
    // ---- 2 chunk-pairs (4 k-chunks of 32) from As[cur]; B ping-pong ----
#pragma unroll
    for (int cp = 0; cp < 2; ++cp) {
      const int kkp = kt2 * 2 + cp;      // chunk-pair 0..15
      const int bc = kkp & 1, bn = bc ^ 1;
      if (kkp + 1 < 16) {  // issue B(kkp+1): in flight through these MFMAs
#pragma unroll
        for (int j = 0; j < 6; ++j) {
          B[bn][j * 2]     = ld_bf8_g(wfb + (((size_t)(nbase + j) * 32 + 2 * (kkp + 1)) << 10));
          B[bn][j * 2 + 1] = ld_bf8_g(wfb + (((size_t)(nbase + j) * 32 + 2 * (kkp + 1) + 1) << 10));
        }
      }
      int row = rhalf + l15;
      bf16x8 a0 = ld_bf8_g(As[cur] + ((row * 256 + cp * 128 + lh * 16) ^ ((row & 7) << 4)));
      bf16x8 a1 = ld_bf8_g(As[cur] + ((row * 256 + cp * 128 + 64 + lh * 16) ^ ((row & 7) << 4)));
#pragma unroll
      for (int j = 0; j < 6; ++j) {
        acc[j] = __builtin_amdgcn_mfma_f32_16x16x32_bf16(a0, B[bc][j * 2], acc[j], 0, 0, 0);
        acc[j] = __builtin_amdgcn_mfma_f32_16x16x32_bf16(a1, B[bc][j * 2 + 1], acc[j], 0, 0, 0);
      }
    }
    if (kt2 < 7) {
      const int s = (kt2 + 1) & 1;       // static under full unroll
      // cvt + write A(kt2+1) into As[nxt]
      ushort8 u0, u1;
#pragma unroll
      for (int e = 0; e < 4; ++e) {
        u0[e] = f2bf(aR[s][0][e]); u0[4 + e] = f2bf(aR[s][1][e]);
        u1[e] = f2bf(aR[s][2][e]); u1[4 + e] = f2bf(aR[s][3][e]);
      }
      *(ushort8*)(As[nxt] + abyte) = u0;
      *(ushort8*)(As[nxt] + (abyte ^ 16)) = u1;
      if (kt2 + 3 < 8) {                 // reuse slot for A(kt2+3)
#pragma unroll
        for (int q4 = 0; q4 < 4; ++q4)
          aR[s][q4] = *(const float4v*)(xp + (kt2 + 3) * 128 + q4 * 4);
      }
      asm volatile("s_waitcnt lgkmcnt(0)" ::: "memory");
      __builtin_amdgcn_s_barrier();
      __builtin_amdgcn_sched_barrier(0);
    }
  }

  // ---- epilogue: bias + scatter to q / K-frag / V-frag ----
#pragma unroll
  for (int cf = 0; cf < 6; ++cf) {
    int col = (nbase + cf) * 16 + l15;
    int sel = col >> 6, c64 = col & 63;
    const float* bias = (sel == 0) ? bq : (sel == 1) ? bk : bv;
    float bb = bias[c64];
    if (sel == 0) {
#pragma unroll
      for (int r = 0; r < 4; ++r) {
        int row = rowBase + rhalf + lh * 4 + r;
        qb[(size_t)row * 64 + c64] = f2bf((acc[cf][r] + bb) * (0.125f * LOG2E));
      }
    } else if (sel == 1) {
      int j16 = c64 >> 4, hik = (c64 >> 3) & 1, e = c64 & 7;
#pragma unroll
      for (int r = 0; r < 4; ++r) {
        int s = rowBase + rhalf + lh * 4 + r;
        int b = s >> 12, sl = s & 4095;
        int ch = sl >> 7, kvw = sl & 127;
        int kvq = kvw >> 5, lk = kvw & 31;
        size_t off = (((size_t)(b * 32 + ch)) << 14) + kvq * 4096 + j16 * 1024 +
                     (hik * 32 + lk) * 16 + e * 2;
        *(unsigned short*)((char*)kreg + off) = f2bf(acc[cf][r] + bb);
      }
    } else {
      ushort4v w;
#pragma unroll
      for (int r = 0; r < 4; ++r) w[r] = f2bf(acc[cf][r] + bb);
      int s0 = rowBase + rhalf + lh * 4;
      int b = s0 >> 12, sl = s0 & 4095;
      int ch = sl >> 7, kvw = sl & 127;
      int kvq = kvw >> 5, k5 = kvw & 31;
      int kj = k5 >> 4, hiv = (k5 >> 3) & 1, e0 = k5 & 7;   // e0 in {0,4}
      int dt = c64 >> 5, lv = c64 & 31, f = kj * 2 + dt;
      size_t off = (((size_t)(b * 32 + ch)) << 14) + kvq * 4096 + f * 1024 +
                   (hiv * 32 + lv) * 16 + e0 * 2;
      *(ushort4v*)((char*)vreg + off) = w;
    }
  }
}

// ---- causal flash attention v14 (R18 verbatim): 8 phases, 1-wave blocks ----
__global__ __launch_bounds__(64, 4) void attn_kernel(
    const unsigned short* __restrict__ qb, const unsigned short* __restrict__ kreg,
    const unsigned short* __restrict__ vreg, float* __restrict__ po,
    float* __restrict__ lo) {
  int lane = threadIdx.x & 63;
  int l31 = lane & 31, hi = lane >> 5;
  int wid = blockIdx.x;
  int T = 127 - (wid >> 5);            // descending tile order (LPT)
  int low = wid & 31;
  int batch = low & 3, ph = low >> 2;  // phase 0..7
  int Tq = T * 32;
  const size_t bO = (size_t)batch * 262144;
  const char* kb = (const char*)kreg + ((size_t)batch << 19);
  const char* vb = (const char*)vreg + ((size_t)batch << 19);

  const unsigned short* qp = qb + bO + (size_t)(Tq + l31) * 64 + hi * 8;
  bf16x8 qf0 = ld_bf8_g(qp);
  bf16x8 qf1 = ld_bf8_g(qp + 16);
  bf16x8 qf2 = ld_bf8_g(qp + 32);
  bf16x8 qf3 = ld_bf8_g(qp + 48);

  f32x16 o0, o1;
#pragma unroll
  for (int r = 0; r < 16; ++r) { o0[r] = 0.f; o1[r] = 0.f; }
  float lsum = 0.f;

#pragma unroll 1
  for (int st = ph; st <= T; st += 8) {
    size_t base = ((size_t)(st >> 2) << 14) + (st & 3) * 4096 + lane * 16;
    const char* kp = kb + base;
    const char* vp = vb + base;
    bf16x8 k0 = ld_bf8_g(kp);
    bf16x8 k1 = ld_bf8_g(kp + 1024);
    bf16x8 k2 = ld_bf8_g(kp + 2048);
    bf16x8 k3 = ld_bf8_g(kp + 3072);
    bf16x8 v0 = ld_bf8_g(vp);
    bf16x8 v1 = ld_bf8_g(vp + 1024);
    bf16x8 v2 = ld_bf8_g(vp + 2048);
    bf16x8 v3 = ld_bf8_g(vp + 3072);

    f32x16 sc;
#pragma unroll
    for (int r = 0; r < 16; ++r) sc[r] = 0.f;
    sc = __builtin_amdgcn_mfma_f32_32x32x16_bf16(k0, qf0, sc, 0, 0, 0);
    sc = __builtin_amdgcn_mfma_f32_32x32x16_bf16(k1, qf1, sc, 0, 0, 0);
    sc = __builtin_amdgcn_mfma_f32_32x32x16_bf16(k2, qf2, sc, 0, 0, 0);
    sc = __builtin_amdgcn_mfma_f32_32x32x16_bf16(k3, qf3, sc, 0, 0, 0);
    if (st == T) {
      int qg = Tq + l31;
#pragma unroll
      for (int r = 0; r < 16; ++r) {
        int kvg = 32 * st + (r & 3) + 8 * (r >> 2) + 4 * hi;
        if (kvg > qg) sc[r] = -3.0e38f;
      }
    }
    float pv[16];
#pragma unroll
    for (int r = 0; r < 16; ++r) {
      pv[r] = fast_exp2(sc[r] - SHIFT_L2);
      lsum += pv[r];
    }
#pragma unroll
    for (int kj = 0; kj < 2; ++kj) {
      const int R = 8 * kj;
      unsigned int A0 = pk2(pv[R + 0], pv[R + 1]);
      unsigned int A1 = pk2(pv[R + 2], pv[R + 3]);
      unsigned int B0 = pk2(pv[R + 4], pv[R + 5]);
      unsigned int B1 = pk2(pv[R + 6], pv[R + 7]);
      unsigned int s0 = hi ? A0 : B0;
      unsigned int s1 = hi ? A1 : B1;
      unsigned int r0 = __shfl_xor((int)s0, 32, 64);
      unsigned int r1 = __shfl_xor((int)s1, 32, 64);
      uint4v dw = {hi ? r0 : A0, hi ? r1 : A1, hi ? B0 : r0, hi ? B1 : r1};
      bf16x8 pa = __builtin_bit_cast(bf16x8, dw);
      if (kj == 0) {
        o0 = __builtin_amdgcn_mfma_f32_32x32x16_bf16(pa, v0, o0, 0, 0, 0);
        o1 = __builtin_amdgcn_mfma_f32_32x32x16_bf16(pa, v1, o1, 0, 0, 0);
      } else {
        o0 = __builtin_amdgcn_mfma_f32_32x32x16_bf16(pa, v2, o0, 0, 0, 0);
        o1 = __builtin_amdgcn_mfma_f32_32x32x16_bf16(pa, v3, o1, 0, 0, 0);
      }
    }
  }

  lsum += __shfl_xor(lsum, 32, 64);

  float* pdst = po + (size_t)ph * 1048576 + bO + (size_t)Tq * 64;
#pragma unroll
  for (int r = 0; r < 16; ++r) {
    int qloc = (r & 3) + 8 * (r >> 2) + 4 * hi;
    pdst[qloc * 64 + l31] = o0[r];
    pdst[qloc * 64 + 32 + l31] = o1[r];
  }
  if (hi == 0) lo[ph * 16384 + batch * 4096 + Tq + l31] = lsum;
}

// ---- merge: out = sum_ph po[ph] / sum_ph lo[ph]  (8 phases) ----------------
__global__ __launch_bounds__(256) void merge_kernel(
    const float* __restrict__ po, const float* __restrict__ lo,
    float* __restrict__ out) {
  int i = blockIdx.x * 256 + threadIdx.x;    // float4 index 0..262143
  int row = i >> 4;                          // 0..16383
  float4v a = ((const float4v*)po)[i];
  float L = lo[row];
#pragma unroll
  for (int ph = 1; ph < 8; ++ph) {
    a += ((const float4v*)po)[i + ph * 262144];
    L += lo[row + ph * 16384];
  }
  a *= (1.0f / L);
  ((float4v*)out)[i] = a;
}

extern "C" void kernel_launch(void* const* d_in, const int* in_sizes, int n_in,
                              void* d_out, int out_size, void* d_ws, size_t ws_size,
                              hipStream_t stream) {
  const float* x  = (const float*)d_in[0];
  const float* wq = (const float*)d_in[1];
  const float* bq = (const float*)d_in[2];
  const float* wk = (const float*)d_in[3];
  const float* bk = (const float*)d_in[4];
  const float* wv = (const float*)d_in[5];
  const float* bv = (const float*)d_in[6];

  unsigned short* Wfrag = (unsigned short*)d_ws;    // 192*1024 (B-frag order)
  unsigned short* qbuf  = Wfrag + 192 * 1024;       // [b*4096+s][64]
  unsigned short* kreg  = qbuf + 16384 * 64;        // 4 x 512 KB fragment-order
  unsigned short* vreg  = kreg + 16384 * 64;        // 4 x 512 KB fragment-order
  float*          po    = (float*)(vreg + 16384 * 64);  // 8 x [4][4096][64]
  float*          lo    = po + 8 * 1048576;             // 8 x [4][4096]

  wprep_kernel<<<768, 256, 0, stream>>>(wq, wk, wv, Wfrag);
  proj_kernel<<<512, 256, 0, stream>>>(x, Wfrag, bq, bk, bv, qbuf, kreg, vreg);
  attn_kernel<<<4096, 64, 0, stream>>>(qbuf, kreg, vreg, po, lo);
  merge_kernel<<<1024, 256, 0, stream>>>(po, lo, (float*)d_out);
}

// Round 23
// 57.269 us; speedup vs baseline: 1.0042x; 1.0042x over previous
//
#include <hip/hip_runtime.h>
#include <hip/hip_bf16.h>

using f32x4    = __attribute__((ext_vector_type(4))) float;
using f32x16   = __attribute__((ext_vector_type(16))) float;
using bf16x8   = __attribute__((ext_vector_type(8))) __bf16;
using ushort8  = __attribute__((ext_vector_type(8))) unsigned short;
using ushort4v = __attribute__((ext_vector_type(4))) unsigned short;
using uint4v   = __attribute__((ext_vector_type(4))) unsigned int;
using float4v  = __attribute__((ext_vector_type(4))) float;

#define LOG2E 1.44269504088896340736f
#define SHIFT_L2 5.77078016355585f   // 4 * log2(e): p = exp(s_true - 4)

static __device__ __forceinline__ unsigned short f2bf(float f) {
  union { __hip_bfloat16 h; unsigned short u; } cv;
  cv.h = __float2bfloat16(f);
  return cv.u;
}
static __device__ __forceinline__ bf16x8 ld_bf8_g(const void* p) {
  ushort8 u = *(const ushort8*)p;
  return __builtin_bit_cast(bf16x8, u);
}
static __device__ __forceinline__ float fast_exp2(float x) {
#if __has_builtin(__builtin_amdgcn_exp2f)
  return __builtin_amdgcn_exp2f(x);
#else
  return exp2f(x);
#endif
}
static __device__ __forceinline__ unsigned int pk2(float a, float b) {
  return (unsigned int)f2bf(a) | ((unsigned int)f2bf(b) << 16);
}

// ---- W prep: Wfrag in MFMA B-fragment order (validated layout) ------------
__global__ __launch_bounds__(256) void wprep_kernel(
    const float* __restrict__ wq, const float* __restrict__ wk,
    const float* __restrict__ wv, unsigned short* __restrict__ Wfrag) {
  int idx = blockIdx.x * 256 + threadIdx.x;   // 0 .. 196607
  int col = idx >> 10;                        // 0..191
  int k   = idx & 1023;
  const float* w = (col < 64) ? wq : (col < 128) ? wk : wv;
  int c = col & 63;
  int n = col >> 4, l15 = col & 15;
  int kk = k >> 5, lh = (k >> 3) & 3, e = k & 7;
  size_t elem = ((size_t)(n * 32 + kk) * 64 + lh * 16 + l15) * 8 + e;
  Wfrag[elem] = f2bf(w[k * 64 + c]);
}

// ---- QKV projection v6: BM=16, 4 blocks/CU (TLP), R19 pipeline ------------
// grid 1024; 4 waves x 3 n-tiles over the SAME 16 rows. B direct-from-L2
// (Wfrag) dbuf regs; A async reg->LDS dbuf (1 float4/thread/step); one raw
// s_barrier + lgkmcnt(0) per 64-k step, no vmcnt drain; fully unrolled.
__global__ __launch_bounds__(256, 4) void proj_kernel(
    const float* __restrict__ x, const unsigned short* __restrict__ Wfrag,
    const float* __restrict__ bq, const float* __restrict__ bk,
    const float* __restrict__ bv,
    unsigned short* __restrict__ qb, unsigned short* __restrict__ kreg,
    unsigned short* __restrict__ vreg) {
  __shared__ __align__(16) char As[2][16 * 128];   // dbuf, swz (row&7)<<4
  int tid = threadIdx.x, wave = tid >> 6, lane = tid & 63;
  int rowBase = blockIdx.x * 16;
  int nbase = wave * 3;                 // 3 n-tiles of 16 cols per wave
  int l15 = lane & 15, lh = lane >> 4;

  int arow = tid >> 4, ac0 = (tid & 15) * 4;   // A-stage: 4 fp32 per thread
  const float* xp = x + (size_t)(rowBase + arow) * 1024 + ac0;
  int abyte = (arow * 128 + ac0 * 2) ^ ((arow & 7) << 4);
  const char* wfb = (const char*)Wfrag + (size_t)lane * 16;

  f32x4 acc[3];
#pragma unroll
  for (int i = 0; i < 3; ++i) acc[i] = (f32x4){0.f, 0.f, 0.f, 0.f};

  float4v aN;                // next A step (depth-1; TLP covers the rest)
  bf16x8 B[2][6];

  // ---- prologue: A(0)->buf0 via temp; A(1) in flight; B(0) regs ----
  {
    float4v t = *(const float4v*)(xp);
#pragma unroll
    for (int j = 0; j < 3; ++j) {
      B[0][j * 2]     = ld_bf8_g(wfb + (((size_t)(nbase + j) * 32 + 0) << 10));
      B[0][j * 2 + 1] = ld_bf8_g(wfb + (((size_t)(nbase + j) * 32 + 1) << 10));
    }
    ushort4v u = {f2bf(t[0]), f2bf(t[1]), f2bf(t[2]), f2bf(t[3])};
    *(ushort4v*)(As[0] + abyte) = u;
  }
  aN = *(const float4v*)(xp + 64);
  asm volatile("s_waitcnt lgkmcnt(0)" ::: "memory");
  __builtin_amdgcn_s_barrier();
  __builtin_amdgcn_sched_barrier(0);

#pragma unroll
  for (int kt = 0; kt < 16; ++kt) {
    const int cur = kt & 1, nxt = cur ^ 1;
    if (kt < 15) {  // issue B(kt+1) — stays in flight through this body
#pragma unroll
      for (int j = 0; j < 3; ++j) {
        B[nxt][j * 2]     = ld_bf8_g(wfb + (((size_t)(nbase + j) * 32 + 2 * (kt + 1)) << 10));
        B[nxt][j * 2 + 1] = ld_bf8_g(wfb + (((size_t)(nbase + j) * 32 + 2 * (kt + 1) + 1) << 10));
      }
    }
    // ---- compute step kt from As[cur] + B[cur] ----
    {
      int row = l15;
      bf16x8 a0 = ld_bf8_g(As[cur] + ((row * 128 + lh * 16) ^ ((row & 7) << 4)));
      bf16x8 a1 = ld_bf8_g(As[cur] + ((row * 128 + 64 + lh * 16) ^ ((row & 7) << 4)));
#pragma unroll
      for (int j = 0; j < 3; ++j) {
        acc[j] = __builtin_amdgcn_mfma_f32_16x16x32_bf16(a0, B[cur][j * 2], acc[j], 0, 0, 0);
        acc[j] = __builtin_amdgcn_mfma_f32_16x16x32_bf16(a1, B[cur][j * 2 + 1], acc[j], 0, 0, 0);
      }
    }
    if (kt < 15) {
      // cvt + write A(kt+1) into As[nxt]; issue A(kt+2)
      ushort4v u = {f2bf(aN[0]), f2bf(aN[1]), f2bf(aN[2]), f2bf(aN[3])};
      *(ushort4v*)(As[nxt] + abyte) = u;
      if (kt < 14) aN = *(const float4v*)(xp + (kt + 2) * 64);
      asm volatile("s_waitcnt lgkmcnt(0)" ::: "memory");
      __builtin_amdgcn_s_barrier();
      __builtin_amdgcn_sched_barrier(0);
    }
  }

  // ---- epilogue: bias + scatter to q / K-frag / V-frag ----
#pragma unroll
  for (int cf = 0; cf < 3; ++cf) {
    int col = (nbase + cf) * 16 + l15;
    int sel = col >> 6, c64 = col & 63;
    const float* bias = (sel == 0) ? bq : (sel == 1) ? bk : bv;
    float bb = bias[c64];
    if (sel == 0) {
#pragma unroll
      for (int r = 0; r < 4; ++r) {
        int row = rowBase + lh * 4 + r;
        qb[(size_t)row * 64 + c64] = f2bf((acc[cf][r] + bb) * (0.125f * LOG2E));
      }
    } else if (sel == 1) {
      int j16 = c64 >> 4, hik = (c64 >> 3) & 1, e = c64 & 7;
#pragma unroll
      for (int r = 0; r < 4; ++r) {
        int s = rowBase + lh * 4 + r;
        int b = s >> 12, sl = s & 4095;
        int ch = sl >> 7, kvw = sl & 127;
        int kvq = kvw >> 5, lk = kvw & 31;
        size_t off = (((size_t)(b * 32 + ch)) << 14) + kvq * 4096 + j16 * 1024 +
                     (hik * 32 + lk) * 16 + e * 2;
        *(unsigned short*)((char*)kreg + off) = f2bf(acc[cf][r] + bb);
      }
    } else {
      ushort4v w;
#pragma unroll
      for (int r = 0; r < 4; ++r) w[r] = f2bf(acc[cf][r] + bb);
      int s0 = rowBase + lh * 4;
      int b = s0 >> 12, sl = s0 & 4095;
      int ch = sl >> 7, kvw = sl & 127;
      int kvq = kvw >> 5, k5 = kvw & 31;
      int kj = k5 >> 4, hiv = (k5 >> 3) & 1, e0 = k5 & 7;   // e0 in {0,4}
      int dt = c64 >> 5, lv = c64 & 31, f = kj * 2 + dt;
      size_t off = (((size_t)(b * 32 + ch)) << 14) + kvq * 4096 + f * 1024 +
                   (hiv * 32 + lv) * 16 + e0 * 2;
      *(ushort4v*)((char*)vreg + off) = w;
    }
  }
}

// ---- causal flash attention v14 (R18 verbatim): 8 phases, 1-wave blocks ----
__global__ __launch_bounds__(64, 4) void attn_kernel(
    const unsigned short* __restrict__ qb, const unsigned short* __restrict__ kreg,
    const unsigned short* __restrict__ vreg, float* __restrict__ po,
    float* __restrict__ lo) {
  int lane = threadIdx.x & 63;
  int l31 = lane & 31, hi = lane >> 5;
  int wid = blockIdx.x;
  int T = 127 - (wid >> 5);            // descending tile order (LPT)
  int low = wid & 31;
  int batch = low & 3, ph = low >> 2;  // phase 0..7
  int Tq = T * 32;
  const size_t bO = (size_t)batch * 262144;
  const char* kb = (const char*)kreg + ((size_t)batch << 19);
  const char* vb = (const char*)vreg + ((size_t)batch << 19);

  const unsigned short* qp = qb + bO + (size_t)(Tq + l31) * 64 + hi * 8;
  bf16x8 qf0 = ld_bf8_g(qp);
  bf16x8 qf1 = ld_bf8_g(qp + 16);
  bf16x8 qf2 = ld_bf8_g(qp + 32);
  bf16x8 qf3 = ld_bf8_g(qp + 48);

  f32x16 o0, o1;
#pragma unroll
  for (int r = 0; r < 16; ++r) { o0[r] = 0.f; o1[r] = 0.f; }
  float lsum = 0.f;

#pragma unroll 1
  for (int st = ph; st <= T; st += 8) {
    size_t base = ((size_t)(st >> 2) << 14) + (st & 3) * 4096 + lane * 16;
    const char* kp = kb + base;
    const char* vp = vb + base;
    bf16x8 k0 = ld_bf8_g(kp);
    bf16x8 k1 = ld_bf8_g(kp + 1024);
    bf16x8 k2 = ld_bf8_g(kp + 2048);
    bf16x8 k3 = ld_bf8_g(kp + 3072);
    bf16x8 v0 = ld_bf8_g(vp);
    bf16x8 v1 = ld_bf8_g(vp + 1024);
    bf16x8 v2 = ld_bf8_g(vp + 2048);
    bf16x8 v3 = ld_bf8_g(vp + 3072);

    f32x16 sc;
#pragma unroll
    for (int r = 0; r < 16; ++r) sc[r] = 0.f;
    sc = __builtin_amdgcn_mfma_f32_32x32x16_bf16(k0, qf0, sc, 0, 0, 0);
    sc = __builtin_amdgcn_mfma_f32_32x32x16_bf16(k1, qf1, sc, 0, 0, 0);
    sc = __builtin_amdgcn_mfma_f32_32x32x16_bf16(k2, qf2, sc, 0, 0, 0);
    sc = __builtin_amdgcn_mfma_f32_32x32x16_bf16(k3, qf3, sc, 0, 0, 0);
    if (st == T) {
      int qg = Tq + l31;
#pragma unroll
      for (int r = 0; r < 16; ++r) {
        int kvg = 32 * st + (r & 3) + 8 * (r >> 2) + 4 * hi;
        if (kvg > qg) sc[r] = -3.0e38f;
      }
    }
    float pv[16];
#pragma unroll
    for (int r = 0; r < 16; ++r) {
      pv[r] = fast_exp2(sc[r] - SHIFT_L2);
      lsum += pv[r];
    }
#pragma unroll
    for (int kj = 0; kj < 2; ++kj) {
      const int R = 8 * kj;
      unsigned int A0 = pk2(pv[R + 0], pv[R + 1]);
      unsigned int A1 = pk2(pv[R + 2], pv[R + 3]);
      unsigned int B0 = pk2(pv[R + 4], pv[R + 5]);
      unsigned int B1 = pk2(pv[R + 6], pv[R + 7]);
      unsigned int s0 = hi ? A0 : B0;
      unsigned int s1 = hi ? A1 : B1;
      unsigned int r0 = __shfl_xor((int)s0, 32, 64);
      unsigned int r1 = __shfl_xor((int)s1, 32, 64);
      uint4v dw = {hi ? r0 : A0, hi ? r1 : A1, hi ? B0 : r0, hi ? B1 : r1};
      bf16x8 pa = __builtin_bit_cast(bf16x8, dw);
      if (kj == 0) {
        o0 = __builtin_amdgcn_mfma_f32_32x32x16_bf16(pa, v0, o0, 0, 0, 0);
        o1 = __builtin_amdgcn_mfma_f32_32x32x16_bf16(pa, v1, o1, 0, 0, 0);
      } else {
        o0 = __builtin_amdgcn_mfma_f32_32x32x16_bf16(pa, v2, o0, 0, 0, 0);
        o1 = __builtin_amdgcn_mfma_f32_32x32x16_bf16(pa, v3, o1, 0, 0, 0);
      }
    }
  }

  lsum += __shfl_xor(lsum, 32, 64);

  float* pdst = po + (size_t)ph * 1048576 + bO + (size_t)Tq * 64;
#pragma unroll
  for (int r = 0; r < 16; ++r) {
    int qloc = (r & 3) + 8 * (r >> 2) + 4 * hi;
    pdst[qloc * 64 + l31] = o0[r];
    pdst[qloc * 64 + 32 + l31] = o1[r];
  }
  if (hi == 0) lo[ph * 16384 + batch * 4096 + Tq + l31] = lsum;
}

// ---- merge: out = sum_ph po[ph] / sum_ph lo[ph]  (8 phases) ----------------
__global__ __launch_bounds__(256) void merge_kernel(
    const float* __restrict__ po, const float* __restrict__ lo,
    float* __restrict__ out) {
  int i = blockIdx.x * 256 + threadIdx.x;    // float4 index 0..262143
  int row = i >> 4;                          // 0..16383
  float4v a = ((const float4v*)po)[i];
  float L = lo[row];
#pragma unroll
  for (int ph = 1; ph < 8; ++ph) {
    a += ((const float4v*)po)[i + ph * 262144];
    L += lo[row + ph * 16384];
  }
  a *= (1.0f / L);
  ((float4v*)out)[i] = a;
}

extern "C" void kernel_launch(void* const* d_in, const int* in_sizes, int n_in,
                              void* d_out, int out_size, void* d_ws, size_t ws_size,
                              hipStream_t stream) {
  const float* x  = (const float*)d_in[0];
  const float* wq = (const float*)d_in[1];
  const float* bq = (const float*)d_in[2];
  const float* wk = (const float*)d_in[3];
  const float* bk = (const float*)d_in[4];
  const float* wv = (const float*)d_in[5];
  const float* bv = (const float*)d_in[6];

  unsigned short* Wfrag = (unsigned short*)d_ws;    // 192*1024 (B-frag order)
  unsigned short* qbuf  = Wfrag + 192 * 1024;       // [b*4096+s][64]
  unsigned short* kreg  = qbuf + 16384 * 64;        // 4 x 512 KB fragment-order
  unsigned short* vreg  = kreg + 16384 * 64;        // 4 x 512 KB fragment-order
  float*          po    = (float*)(vreg + 16384 * 64);  // 8 x [4][4096][64]
  float*          lo    = po + 8 * 1048576;             // 8 x [4][4096]

  wprep_kernel<<<768, 256, 0, stream>>>(wq, wk, wv, Wfrag);
  proj_kernel<<<1024, 256, 0, stream>>>(x, Wfrag, bq, bk, bv, qbuf, kreg, vreg);
  attn_kernel<<<4096, 64, 0, stream>>>(qbuf, kreg, vreg, po, lo);
  merge_kernel<<<1024, 256, 0, stream>>>(po, lo, (float*)d_out);
}

// Round 24
// 55.288 us; speedup vs baseline: 1.0402x; 1.0358x over previous
//
#include <hip/hip_runtime.h>
#include <hip/hip_bf16.h>

using f32x4    = __attribute__((ext_vector_type(4))) float;
using f32x16   = __attribute__((ext_vector_type(16))) float;
using bf16x8   = __attribute__((ext_vector_type(8))) __bf16;
using ushort8  = __attribute__((ext_vector_type(8))) unsigned short;
using ushort4v = __attribute__((ext_vector_type(4))) unsigned short;
using uint4v   = __attribute__((ext_vector_type(4))) unsigned int;
using float4v  = __attribute__((ext_vector_type(4))) float;

#define LOG2E 1.44269504088896340736f
#define SHIFT_L2 5.77078016355585f   // 4 * log2(e): p = exp(s_true - 4)

static __device__ __forceinline__ unsigned short f2bf(float f) {
  union { __hip_bfloat16 h; unsigned short u; } cv;
  cv.h = __float2bfloat16(f);
  return cv.u;
}
static __device__ __forceinline__ bf16x8 ld_bf8_g(const void* p) {
  ushort8 u = *(const ushort8*)p;
  return __builtin_bit_cast(bf16x8, u);
}
static __device__ __forceinline__ float fast_exp2(float x) {
#if __has_builtin(__builtin_amdgcn_exp2f)
  return __builtin_amdgcn_exp2f(x);
#else
  return exp2f(x);
#endif
}
static __device__ __forceinline__ unsigned int pk2(float a, float b) {
  return (unsigned int)f2bf(a) | ((unsigned int)f2bf(b) << 16);
}

// ---- W prep: Wfrag in MFMA B-fragment order (R15 layout, validated) -------
__global__ __launch_bounds__(256) void wprep_kernel(
    const float* __restrict__ wq, const float* __restrict__ wk,
    const float* __restrict__ wv, unsigned short* __restrict__ Wfrag) {
  int idx = blockIdx.x * 256 + threadIdx.x;   // 0 .. 196607
  int col = idx >> 10;                        // 0..191
  int k   = idx & 1023;
  const float* w = (col < 64) ? wq : (col < 128) ? wk : wv;
  int c = col & 63;
  int n = col >> 4, l15 = col & 15;
  int kk = k >> 5, lh = (k >> 3) & 3, e = k & 7;
  size_t elem = ((size_t)(n * 32 + kk) * 64 + lh * 16 + l15) * 8 + e;
  Wfrag[elem] = f2bf(w[k * 64 + c]);
}

// ---- QKV projection v2 (R19, measured best): pipelined --------------------
// B direct-from-L2 dbuf regs; A async reg->LDS dbuf; one raw s_barrier +
// lgkmcnt(0) per step, no vmcnt drain. BM=32, BN=192.
__global__ __launch_bounds__(256, 2) void proj_kernel(
    const float* __restrict__ x, const unsigned short* __restrict__ Wfrag,
    const float* __restrict__ bq, const float* __restrict__ bk,
    const float* __restrict__ bv,
    unsigned short* __restrict__ qb, unsigned short* __restrict__ kreg,
    unsigned short* __restrict__ vreg) {
  __shared__ __align__(16) char As[2][32 * 128];   // dbuf, swz (row&7)<<4
  int tid = threadIdx.x, wave = tid >> 6, lane = tid & 63;
  int rowBase = blockIdx.x * 32;
  int rhalf = (wave & 1) * 16;
  int nbase = (wave >> 1) * 6;          // 6 n-tiles of 16 cols per wave-pair
  int l15 = lane & 15, lh = lane >> 4;

  int arow = tid >> 3, ac0 = (tid & 7) * 8;   // A-stage: 8 fp32 per thread
  const float* xp = x + (size_t)(rowBase + arow) * 1024 + ac0;
  int abyte = (arow * 128 + ac0 * 2) ^ ((arow & 7) << 4);
  const char* wfb = (const char*)Wfrag + (size_t)lane * 16;

  f32x4 acc[6];
#pragma unroll
  for (int i = 0; i < 6; ++i) acc[i] = (f32x4){0.f, 0.f, 0.f, 0.f};

  float4v aL[2], aH[2];
  bf16x8 B[2][12];

  // ---- prologue: A(0)->buf0, B(0) in regs, A(1) in flight ----
  aL[0] = *(const float4v*)(xp);
  aH[0] = *(const float4v*)(xp + 4);
#pragma unroll
  for (int j = 0; j < 6; ++j) {
    B[0][j * 2]     = ld_bf8_g(wfb + (((size_t)(nbase + j) * 32 + 0) << 10));
    B[0][j * 2 + 1] = ld_bf8_g(wfb + (((size_t)(nbase + j) * 32 + 1) << 10));
  }
  {
    ushort8 u;
#pragma unroll
    for (int e = 0; e < 4; ++e) { u[e] = f2bf(aL[0][e]); u[4 + e] = f2bf(aH[0][e]); }
    *(ushort8*)(As[0] + abyte) = u;
  }
  aL[1] = *(const float4v*)(xp + 64);
  aH[1] = *(const float4v*)(xp + 68);
  asm volatile("s_waitcnt lgkmcnt(0)" ::: "memory");
  __builtin_amdgcn_s_barrier();
  __builtin_amdgcn_sched_barrier(0);

#pragma unroll
  for (int kt = 0; kt < 16; ++kt) {
    const int cur = kt & 1, nxt = cur ^ 1;
    if (kt < 15) {  // issue B(kt+1) — stays in flight through this body
#pragma unroll
      for (int j = 0; j < 6; ++j) {
        B[nxt][j * 2]     = ld_bf8_g(wfb + (((size_t)(nbase + j) * 32 + 2 * (kt + 1)) << 10));
        B[nxt][j * 2 + 1] = ld_bf8_g(wfb + (((size_t)(nbase + j) * 32 + 2 * (kt + 1) + 1) << 10));
      }
    }
    // ---- compute step kt from As[cur] + B[cur] ----
    {
      int row = rhalf + l15;
      bf16x8 a0 = ld_bf8_g(As[cur] + ((row * 128 + lh * 16) ^ ((row & 7) << 4)));
      bf16x8 a1 = ld_bf8_g(As[cur] + ((row * 128 + 64 + lh * 16) ^ ((row & 7) << 4)));
#pragma unroll
      for (int j = 0; j < 6; ++j) {
        acc[j] = __builtin_amdgcn_mfma_f32_16x16x32_bf16(a0, B[cur][j * 2], acc[j], 0, 0, 0);
        acc[j] = __builtin_amdgcn_mfma_f32_16x16x32_bf16(a1, B[cur][j * 2 + 1], acc[j], 0, 0, 0);
      }
    }
    if (kt < 15) {
      // cvt + write A(kt+1) into As[nxt]; issue A(kt+2)
      ushort8 u;
#pragma unroll
      for (int e = 0; e < 4; ++e) { u[e] = f2bf(aL[nxt][e]); u[4 + e] = f2bf(aH[nxt][e]); }
      *(ushort8*)(As[nxt] + abyte) = u;
      if (kt < 14) {
        aL[cur] = *(const float4v*)(xp + (kt + 2) * 64);
        aH[cur] = *(const float4v*)(xp + (kt + 2) * 64 + 4);
      }
      asm volatile("s_waitcnt lgkmcnt(0)" ::: "memory");
      __builtin_amdgcn_s_barrier();
      __builtin_amdgcn_sched_barrier(0);
    }
  }

  // ---- epilogue: bias + scatter to q / K-frag / V-frag ----
#pragma unroll
  for (int cf = 0; cf < 6; ++cf) {
    int col = (nbase + cf) * 16 + l15;
    int sel = col >> 6, c64 = col & 63;
    const float* bias = (sel == 0) ? bq : (sel == 1) ? bk : bv;
    float bb = bias[c64];
    if (sel == 0) {
#pragma unroll
      for (int r = 0; r < 4; ++r) {
        int row = rowBase + rhalf + lh * 4 + r;
        qb[(size_t)row * 64 + c64] = f2bf((acc[cf][r] + bb) * (0.125f * LOG2E));
      }
    } else if (sel == 1) {
      int j16 = c64 >> 4, hik = (c64 >> 3) & 1, e = c64 & 7;
#pragma unroll
      for (int r = 0; r < 4; ++r) {
        int s = rowBase + rhalf + lh * 4 + r;
        int b = s >> 12, sl = s & 4095;
        int ch = sl >> 7, kvw = sl & 127;
        int kvq = kvw >> 5, lk = kvw & 31;
        size_t off = (((size_t)(b * 32 + ch)) << 14) + kvq * 4096 + j16 * 1024 +
                     (hik * 32 + lk) * 16 + e * 2;
        *(unsigned short*)((char*)kreg + off) = f2bf(acc[cf][r] + bb);
      }
    } else {
      ushort4v w;
#pragma unroll
      for (int r = 0; r < 4; ++r) w[r] = f2bf(acc[cf][r] + bb);
      int s0 = rowBase + rhalf + lh * 4;
      int b = s0 >> 12, sl = s0 & 4095;
      int ch = sl >> 7, kvw = sl & 127;
      int kvq = kvw >> 5, k5 = kvw & 31;
      int kj = k5 >> 4, hiv = (k5 >> 3) & 1, e0 = k5 & 7;   // e0 in {0,4}
      int dt = c64 >> 5, lv = c64 & 31, f = kj * 2 + dt;
      size_t off = (((size_t)(b * 32 + ch)) << 14) + kvq * 4096 + f * 1024 +
                   (hiv * 32 + lv) * 16 + e0 * 2;
      *(ushort4v*)((char*)vreg + off) = w;
    }
  }
}

// ---- causal flash attention v14 (R18 verbatim): 8 phases, 1-wave blocks ----
__global__ __launch_bounds__(64, 4) void attn_kernel(
    const unsigned short* __restrict__ qb, const unsigned short* __restrict__ kreg,
    const unsigned short* __restrict__ vreg, float* __restrict__ po,
    float* __restrict__ lo) {
  int lane = threadIdx.x & 63;
  int l31 = lane & 31, hi = lane >> 5;
  int wid = blockIdx.x;
  int T = 127 - (wid >> 5);            // descending tile order (LPT)
  int low = wid & 31;
  int batch = low & 3, ph = low >> 2;  // phase 0..7
  int Tq = T * 32;
  const size_t bO = (size_t)batch * 262144;
  const char* kb = (const char*)kreg + ((size_t)batch << 19);
  const char* vb = (const char*)vreg + ((size_t)batch << 19);

  const unsigned short* qp = qb + bO + (size_t)(Tq + l31) * 64 + hi * 8;
  bf16x8 qf0 = ld_bf8_g(qp);
  bf16x8 qf1 = ld_bf8_g(qp + 16);
  bf16x8 qf2 = ld_bf8_g(qp + 32);
  bf16x8 qf3 = ld_bf8_g(qp + 48);

  f32x16 o0, o1;
#pragma unroll
  for (int r = 0; r < 16; ++r) { o0[r] = 0.f; o1[r] = 0.f; }
  float lsum = 0.f;

#pragma unroll 1
  for (int st = ph; st <= T; st += 8) {
    size_t base = ((size_t)(st >> 2) << 14) + (st & 3) * 4096 + lane * 16;
    const char* kp = kb + base;
    const char* vp = vb + base;
    bf16x8 k0 = ld_bf8_g(kp);
    bf16x8 k1 = ld_bf8_g(kp + 1024);
    bf16x8 k2 = ld_bf8_g(kp + 2048);
    bf16x8 k3 = ld_bf8_g(kp + 3072);
    bf16x8 v0 = ld_bf8_g(vp);
    bf16x8 v1 = ld_bf8_g(vp + 1024);
    bf16x8 v2 = ld_bf8_g(vp + 2048);
    bf16x8 v3 = ld_bf8_g(vp + 3072);

    f32x16 sc;
#pragma unroll
    for (int r = 0; r < 16; ++r) sc[r] = 0.f;
    sc = __builtin_amdgcn_mfma_f32_32x32x16_bf16(k0, qf0, sc, 0, 0, 0);
    sc = __builtin_amdgcn_mfma_f32_32x32x16_bf16(k1, qf1, sc, 0, 0, 0);
    sc = __builtin_amdgcn_mfma_f32_32x32x16_bf16(k2, qf2, sc, 0, 0, 0);
    sc = __builtin_amdgcn_mfma_f32_32x32x16_bf16(k3, qf3, sc, 0, 0, 0);
    if (st == T) {
      int qg = Tq + l31;
#pragma unroll
      for (int r = 0; r < 16; ++r) {
        int kvg = 32 * st + (r & 3) + 8 * (r >> 2) + 4 * hi;
        if (kvg > qg) sc[r] = -3.0e38f;
      }
    }
    float pv[16];
#pragma unroll
    for (int r = 0; r < 16; ++r) {
      pv[r] = fast_exp2(sc[r] - SHIFT_L2);
      lsum += pv[r];
    }
#pragma unroll
    for (int kj = 0; kj < 2; ++kj) {
      const int R = 8 * kj;
      unsigned int A0 = pk2(pv[R + 0], pv[R + 1]);
      unsigned int A1 = pk2(pv[R + 2], pv[R + 3]);
      unsigned int B0 = pk2(pv[R + 4], pv[R + 5]);
      unsigned int B1 = pk2(pv[R + 6], pv[R + 7]);
      unsigned int s0 = hi ? A0 : B0;
      unsigned int s1 = hi ? A1 : B1;
      unsigned int r0 = __shfl_xor((int)s0, 32, 64);
      unsigned int r1 = __shfl_xor((int)s1, 32, 64);
      uint4v dw = {hi ? r0 : A0, hi ? r1 : A1, hi ? B0 : r0, hi ? B1 : r1};
      bf16x8 pa = __builtin_bit_cast(bf16x8, dw);
      if (kj == 0) {
        o0 = __builtin_amdgcn_mfma_f32_32x32x16_bf16(pa, v0, o0, 0, 0, 0);
        o1 = __builtin_amdgcn_mfma_f32_32x32x16_bf16(pa, v1, o1, 0, 0, 0);
      } else {
        o0 = __builtin_amdgcn_mfma_f32_32x32x16_bf16(pa, v2, o0, 0, 0, 0);
        o1 = __builtin_amdgcn_mfma_f32_32x32x16_bf16(pa, v3, o1, 0, 0, 0);
      }
    }
  }

  lsum += __shfl_xor(lsum, 32, 64);

  float* pdst = po + (size_t)ph * 1048576 + bO + (size_t)Tq * 64;
#pragma unroll
  for (int r = 0; r < 16; ++r) {
    int qloc = (r & 3) + 8 * (r >> 2) + 4 * hi;
    pdst[qloc * 64 + l31] = o0[r];
    pdst[qloc * 64 + 32 + l31] = o1[r];
  }
  if (hi == 0) lo[ph * 16384 + batch * 4096 + Tq + l31] = lsum;
}

// ---- merge: out = sum_ph po[ph] / sum_ph lo[ph]  (8 phases) ----------------
__global__ __launch_bounds__(256) void merge_kernel(
    const float* __restrict__ po, const float* __restrict__ lo,
    float* __restrict__ out) {
  int i = blockIdx.x * 256 + threadIdx.x;    // float4 index 0..262143
  int row = i >> 4;                          // 0..16383
  float4v a = ((const float4v*)po)[i];
  float L = lo[row];
#pragma unroll
  for (int ph = 1; ph < 8; ++ph) {
    a += ((const float4v*)po)[i + ph * 262144];
    L += lo[row + ph * 16384];
  }
  a *= (1.0f / L);
  ((float4v*)out)[i] = a;
}

extern "C" void kernel_launch(void* const* d_in, const int* in_sizes, int n_in,
                              void* d_out, int out_size, void* d_ws, size_t ws_size,
                              hipStream_t stream) {
  const float* x  = (const float*)d_in[0];
  const float* wq = (const float*)d_in[1];
  const float* bq = (const float*)d_in[2];
  const float* wk = (const float*)d_in[3];
  const float* bk = (const float*)d_in[4];
  const float* wv = (const float*)d_in[5];
  const float* bv = (const float*)d_in[6];

  unsigned short* Wfrag = (unsigned short*)d_ws;    // 192*1024 (B-frag order)
  unsigned short* qbuf  = Wfrag + 192 * 1024;       // [b*4096+s][64]
  unsigned short* kreg  = qbuf + 16384 * 64;        // 4 x 512 KB fragment-order
  unsigned short* vreg  = kreg + 16384 * 64;        // 4 x 512 KB fragment-order
  float*          po    = (float*)(vreg + 16384 * 64);  // 8 x [4][4096][64]
  float*          lo    = po + 8 * 1048576;             // 8 x [4][4096]

  wprep_kernel<<<768, 256, 0, stream>>>(wq, wk, wv, Wfrag);
  proj_kernel<<<512, 256, 0, stream>>>(x, Wfrag, bq, bk, bv, qbuf, kreg, vreg);
  attn_kernel<<<4096, 64, 0, stream>>>(qbuf, kreg, vreg, po, lo);
  merge_kernel<<<1024, 256, 0, stream>>>(po, lo, (float*)d_out);
}